// Round 7
// baseline (170.458 us; speedup 1.0000x reference)
//
#include <hip/hip_runtime.h>
#include <hip/hip_bf16.h>

using bf16 = __hip_bfloat16;
typedef __attribute__((ext_vector_type(4))) float f32x4;
typedef __attribute__((ext_vector_type(8))) short short8;

#define SEQ 4096
#define DIM 768

// r16: T3-minimum pipeline in gemm_core_t (all three GEMMs): 3-buffer LDS
// ring (3x8KB per operand, 48KB total -> still 3 blocks/CU), depth-2
// prefetch (stage chunk t+2 BEFORE computing chunk t), ONE barrier per
// 32-K chunk, counted s_waitcnt vmcnt(4) in steady state (never 0
// mid-loop). Removes the full vmcnt drain __syncthreads imposed before
// every compute phase (m114: ~20% all-wait). Layouts/epilogues frozen
// (r14 tiled layout: 0 bank conflicts, contiguous-1KB staging).
// r15: 167.6us; predicted ~155-158us, absmax bit-identical.

__device__ __forceinline__ size_t tiled_off(int r, int c, int K) {
  // bf16-element offset of (r,c) in a fragment-tiled [R][K] matrix
  return (size_t)(r >> 4) * 16 * K + ((size_t)(c >> 5) << 9) +
         (size_t)((((c >> 3) & 3) << 4) + (r & 15)) * 8 + (c & 7);
}

// ---- fused fp32 -> bf16 canonicalization (RNE) + denom zeroing ----
// writes bf16 in fragment-tiled layout (16B chunks -> one slot each)
__global__ void convert_all_kernel(const float* __restrict__ x,
                                   const float* __restrict__ wq,
                                   const float* __restrict__ wk,
                                   const float* __restrict__ wv,
                                   bf16* __restrict__ xc, bf16* __restrict__ wqc,
                                   bf16* __restrict__ wkc, bf16* __restrict__ wvc,
                                   float* __restrict__ denom) {
  const int XB = (SEQ * DIM) / 2048;   // 1536
  const int WB = (DIM * DIM) / 2048;   // 288
  int b = blockIdx.x;
  if (b == 0) {  // zero denom[4096]
    float4 z = {0.f, 0.f, 0.f, 0.f};
#pragma unroll
    for (int q = 0; q < 4; q++)
      *(float4*)(denom + threadIdx.x * 4 + q * 1024) = z;
  }
  const float* src; bf16* dst; int off;
  if (b < XB)               { src = x;  dst = xc;  off = b * 2048; }
  else if (b < XB + WB)     { src = wq; dst = wqc; off = (b - XB) * 2048; }
  else if (b < XB + 2 * WB) { src = wk; dst = wkc; off = (b - XB - WB) * 2048; }
  else                      { src = wv; dst = wvc; off = (b - XB - 2 * WB) * 2048; }
  int i = off + threadIdx.x * 8;       // flat index; 8 | i
  float4 f0 = *(const float4*)(src + i);
  float4 f1 = *(const float4*)(src + i + 4);
  bf16 tmp[8];
  tmp[0] = __float2bfloat16(f0.x); tmp[1] = __float2bfloat16(f0.y);
  tmp[2] = __float2bfloat16(f0.z); tmp[3] = __float2bfloat16(f0.w);
  tmp[4] = __float2bfloat16(f1.x); tmp[5] = __float2bfloat16(f1.y);
  tmp[6] = __float2bfloat16(f1.z); tmp[7] = __float2bfloat16(f1.w);
  int r = i / DIM, c = i % DIM;        // c multiple of 8
  *(uint4*)(dst + tiled_off(r, c, DIM)) = *(const uint4*)tmp;
}

// ============ shared helpers ============
__device__ __forceinline__ void gload_lds16(const bf16* g, bf16* l) {
  __builtin_amdgcn_global_load_lds(
      (const __attribute__((address_space(1))) void*)g,
      (__attribute__((address_space(3))) void*)l,
      16, 0, 0);
}

// ============ BT-GEMM core, tiled operands, T3-min pipeline ============
// LDS: lA = 3 ring buffers x 4096 bf16 (8KB each); lB same at +12288.
// Per 32-K chunk per wave: 4 gloads (2 A-subtiles + 2 B-subtiles).
// Stage chunk t+2 before computing chunk t; vmcnt(4) = chunk t+1 landed,
// chunk t+2's 4 loads stay in flight across the barrier.
__device__ __forceinline__ void gct_stage(const bf16* __restrict__ At,
                                          const bf16* __restrict__ Bt,
                                          int rtA, int rtB, int Kblk, int kt,
                                          int buf, bf16* lA, bf16* lB,
                                          int wave, int lane) {
#pragma unroll
  for (int s = 0; s < 2; s++) {
    const int st = wave * 2 + s;   // subtile 0..7 (rows st*16..st*16+16)
    gload_lds16(At + ((size_t)(rtA + st) * Kblk + kt) * 512 + lane * 8,
                lA + buf * 4096 + st * 512);
    gload_lds16(Bt + ((size_t)(rtB + st) * Kblk + kt) * 512 + lane * 8,
                lB + buf * 4096 + st * 512);
  }
}

__device__ __forceinline__ void gemm_core_t(const bf16* __restrict__ At,
                                            const bf16* __restrict__ Bt,
                                            int Kblk /* K/32 */, int nkt,
                                            int m0, int n0, int kt0,
                                            f32x4 acc[4][4],
                                            bf16* lA, bf16* lB) {
  const int tid  = threadIdx.x;
  const int wave = tid >> 6, lane = tid & 63;
  const int sma = (wave & 1) * 4;   // A subtile base (0 or 4)
  const int smb = (wave >> 1) * 4;  // B subtile base
  const int rtA = m0 >> 4, rtB = n0 >> 4;

  // prologue: stage chunks 0 and 1 (nkt >= 2 always here)
  gct_stage(At, Bt, rtA, rtB, Kblk, kt0 + 0, 0, lA, lB, wave, lane);
  gct_stage(At, Bt, rtA, rtB, Kblk, kt0 + 1, 1, lA, lB, wave, lane);
  asm volatile("s_waitcnt vmcnt(4)" ::: "memory");  // chunk 0 landed
  __builtin_amdgcn_s_barrier();

  for (int t = 0; t < nkt; ++t) {
    const int b_ = t % 3;
    if (t + 2 < nkt)
      gct_stage(At, Bt, rtA, rtB, Kblk, kt0 + t + 2, (t + 2) % 3,
                lA, lB, wave, lane);
    short8 af[4], bfr[4];
#pragma unroll
    for (int i = 0; i < 4; i++)
      af[i] = *(const short8*)&lA[b_ * 4096 + (sma + i) * 512 + lane * 8];
#pragma unroll
    for (int j = 0; j < 4; j++)
      bfr[j] = *(const short8*)&lB[b_ * 4096 + (smb + j) * 512 + lane * 8];
#pragma unroll
    for (int i = 0; i < 4; i++)
#pragma unroll
      for (int j = 0; j < 4; j++)
        acc[i][j] = __builtin_amdgcn_mfma_f32_16x16x32_bf16(af[i], bfr[j], acc[i][j], 0, 0, 0);
    if (t + 2 < nkt) {
      asm volatile("s_waitcnt vmcnt(4)" ::: "memory");  // chunk t+1 landed
    } else {
      asm volatile("s_waitcnt vmcnt(0)" ::: "memory");  // tail drain
    }
    __builtin_amdgcn_s_barrier();
  }
}

// C/D layout (verified m89/m91): col = lane&15, row = (lane>>4)*4 + reg.

// ---- K1: fused QKV projection. grid (32, 18), XCD-swizzled. Q gets softmax
// scale folded; Q/Kb written fragment-tiled; V written transposed+tiled.
__global__ __launch_bounds__(256, 3) void qkv_kernel(
    const bf16* __restrict__ x, const bf16* __restrict__ Wq,
    const bf16* __restrict__ Wk, const bf16* __restrict__ Wv,
    bf16* __restrict__ Q, bf16* __restrict__ Kb, bf16* __restrict__ Vt) {
  __shared__ __align__(16) bf16 smem[24576];  // 48KB: lA ring | lB ring
  bf16* lA = smem;
  bf16* lB = smem + 12288;
  // swizzle: XCD (id%8) gets m-slab of 4 tiles x all 18 n-tiles (x-slab hot in L2)
  const int id  = blockIdx.y * 32 + blockIdx.x;  // 0..575
  const int xcd = id & 7;
  const int k   = id >> 3;                       // 0..71
  const int m0  = (xcd * 4 + (k & 3)) * 128;
  const int n0g = (k >> 2) * 128;                // 0..17 tiles
  const int wsel = n0g / DIM;          // 0=Q 1=K 2=V (uniform per block)
  const int n0   = n0g % DIM;
  const bf16* W = (wsel == 0) ? Wq : (wsel == 1) ? Wk : Wv;
  f32x4 acc[4][4] = {};
  gemm_core_t(x, W, DIM / 32, DIM / 32, m0, n0, 0, acc, lA, lB);

  const int tid = threadIdx.x, wave = tid >> 6, lane = tid & 63;
  const int wm = (wave & 1) * 64, wn = (wave >> 1) * 64;
  const int g = lane >> 4, lr = lane & 15;
  const float scale = 0.03608439182435161f;  // 1/sqrt(768)

  if (wsel == 2) {
    // Two-phase 128x64 LDS transpose; stride 67 spreads banks.
    bf16* tile = smem;
#pragma unroll
    for (int ph = 0; ph < 2; ph++) {
      __syncthreads();
      if ((wave >> 1) == ph) {
#pragma unroll
        for (int i = 0; i < 4; i++)
#pragma unroll
          for (int j = 0; j < 4; j++)
#pragma unroll
            for (int r = 0; r < 4; r++)
              tile[(wm + i * 16 + g * 4 + r) * 67 + j * 16 + lr] =
                  __float2bfloat16(acc[i][j][r]);
      }
      __syncthreads();
      int cl = tid >> 2;          // column within this 64-col half
      int r0 = (tid & 3) * 32;    // row segment (mult of 32)
      bf16 vals[32];
#pragma unroll
      for (int q = 0; q < 32; q++) vals[q] = tile[(r0 + q) * 67 + cl];
      // Vt fragment-tiled: row n (V output col), k = seq (m0+r0+q), K=SEQ.
      int n = n0 + ph * 64 + cl;
      size_t vbase = (size_t)(n >> 4) * 16 * SEQ +
                     ((size_t)((m0 + r0) >> 5) << 9) + (size_t)(n & 15) * 8;
#pragma unroll
      for (int qb = 0; qb < 4; qb++)   // chunk qb -> +qb*16 slots = +qb*128 elems
        *(uint4*)(Vt + vbase + qb * 128) = *(const uint4*)(vals + qb * 8);
    }
  } else {
    bf16* dstm = (wsel == 0) ? Q : Kb;
    float fs = (wsel == 0) ? scale : 1.0f;
#pragma unroll
    for (int i = 0; i < 4; i++)
#pragma unroll
      for (int j = 0; j < 4; j++)
#pragma unroll
        for (int r = 0; r < 4; r++) {
          int row = m0 + wm + i * 16 + g * 4 + r;
          int col = n0 + wn + j * 16 + lr;
          dstm[tiled_off(row, col, DIM)] = __float2bfloat16(acc[i][j][r] * fs);
        }
  }
}

// ---- K2: S = Q K^T; P = exp(S); row sums -> denom. grid (32,32),
// XCD-swizzled, pipelined 128^2 core on tiled Q/Kb; P written tiled.
__global__ __launch_bounds__(256, 3) void score_kernel(
    const bf16* __restrict__ Q, const bf16* __restrict__ Kb,
    bf16* __restrict__ P, float* __restrict__ denom) {
  __shared__ __align__(16) bf16 smem[24576];
  bf16* lA = smem;
  bf16* lB = smem + 12288;
  // swizzle: XCD (id%8) gets m-slab of 4 Q-tiles (L2-hot) x all 32 n.
  const int id  = blockIdx.y * 32 + blockIdx.x;  // 0..1023
  const int xcd = id & 7;
  const int k   = id >> 3;                       // 0..127
  const int m0  = (xcd * 4 + (k & 3)) * 128;
  const int n0  = (k >> 2) * 128;
  f32x4 acc[4][4] = {};
  gemm_core_t(Q, Kb, DIM / 32, DIM / 32, m0, n0, 0, acc, lA, lB);

  const int tid = threadIdx.x, wave = tid >> 6, lane = tid & 63;
  const int wm = (wave & 1) * 64, wn = (wave >> 1) * 64;
  const int g = lane >> 4, lr = lane & 15;
#pragma unroll
  for (int i = 0; i < 4; i++) {
    float rsum[4] = {0.f, 0.f, 0.f, 0.f};
#pragma unroll
    for (int j = 0; j < 4; j++)
#pragma unroll
      for (int r = 0; r < 4; r++) {
        float p = __expf(acc[i][j][r]);
        int row = m0 + wm + i * 16 + g * 4 + r;
        int col = n0 + wn + j * 16 + lr;
        P[tiled_off(row, col, SEQ)] = __float2bfloat16(p);
        rsum[r] += p;
      }
#pragma unroll
    for (int r = 0; r < 4; r++) {
      float s = rsum[r];
      s += __shfl_xor(s, 1);
      s += __shfl_xor(s, 2);
      s += __shfl_xor(s, 4);
      s += __shfl_xor(s, 8);
      if (lr == 0) atomicAdd(&denom[m0 + wm + i * 16 + g * 4 + r], s);
    }
  }
}

// ---- K3a: split-K PV. grid (32, 6, 4), XCD-swizzled. bf16 partials
// (row-major, consumed linearly by reduce).
__global__ __launch_bounds__(256, 3) void pv_kernel(
    const bf16* __restrict__ P, const bf16* __restrict__ Vt,
    bf16* __restrict__ partial) {
  __shared__ __align__(16) bf16 smem[24576];
  bf16* lA = smem;
  bf16* lB = smem + 12288;
  // swizzle: XCD gets 3 (z,n) pairs x all 32 m: Vt chunk L2-hot
  // across the 32 consecutive same-XCD blocks that reuse it.
  const int id  = (blockIdx.z * 6 + blockIdx.y) * 32 + blockIdx.x;  // 0..767
  const int xcd = id & 7;
  const int k   = id >> 3;          // 0..95
  const int m0  = (k & 31) * 128;
  const int pairid = xcd * 3 + (k >> 5);  // 0..23
  const int zz  = pairid / 6;
  const int n0  = (pairid % 6) * 128;
  f32x4 acc[4][4] = {};
  // K-window: kts [zz*32, zz*32+32) of SEQ/32=128
  gemm_core_t(P, Vt, SEQ / 32, 32, m0, n0, zz * 32, acc, lA, lB);

  bf16* pout = partial + (size_t)zz * SEQ * DIM;
  const int tid = threadIdx.x, wave = tid >> 6, lane = tid & 63;
  const int wm = (wave & 1) * 64, wn = (wave >> 1) * 64;
  const int g = lane >> 4, lr = lane & 15;
#pragma unroll
  for (int i = 0; i < 4; i++)
#pragma unroll
    for (int j = 0; j < 4; j++)
#pragma unroll
      for (int r = 0; r < 4; r++) {
        int row = m0 + wm + i * 16 + g * 4 + r;
        int col = n0 + wn + j * 16 + lr;
        pout[row * DIM + col] = __float2bfloat16(acc[i][j][r]);
      }
}

// ---- K3b: out = (sum_z partial[z]) / denom[row]. 8 elems/thread.
__global__ __launch_bounds__(256) void reduce_kernel(
    const bf16* __restrict__ partial, const float* __restrict__ denom,
    float* __restrict__ out) {
  const size_t stride = (size_t)SEQ * DIM;
  int i = (blockIdx.x * 256 + threadIdx.x) * 8;
  uint4 u0 = *(const uint4*)(partial + i);
  uint4 u1 = *(const uint4*)(partial + stride + i);
  uint4 u2 = *(const uint4*)(partial + 2 * stride + i);
  uint4 u3 = *(const uint4*)(partial + 3 * stride + i);
  bf16 a0[8], a1[8], a2[8], a3[8];
  *(uint4*)a0 = u0; *(uint4*)a1 = u1; *(uint4*)a2 = u2; *(uint4*)a3 = u3;
  float inv = 1.0f / denom[i / DIM];   // 8 | DIM: all 8 elems same row
  float o[8];
#pragma unroll
  for (int k = 0; k < 8; k++)
    o[k] = (__bfloat162float(a0[k]) + __bfloat162float(a1[k]) +
            __bfloat162float(a2[k]) + __bfloat162float(a3[k])) * inv;
  *(float4*)(out + i)     = *(const float4*)(o);
  *(float4*)(out + i + 4) = *(const float4*)(o + 4);
}

extern "C" void kernel_launch(void* const* d_in, const int* in_sizes, int n_in,
                              void* d_out, int out_size, void* d_ws, size_t ws_size,
                              hipStream_t stream) {
  const float* x_raw  = (const float*)d_in[0];
  const float* Wq_raw = (const float*)d_in[1];
  const float* Wk_raw = (const float*)d_in[2];
  const float* Wv_raw = (const float*)d_in[3];
  float* out = (float*)d_out;

  // ws layout (~86 MB): all GEMM operands fragment-tiled (same sizes)
  bf16* xc  = (bf16*)d_ws;
  bf16* Wqc = xc  + (size_t)SEQ * DIM;
  bf16* Wkc = Wqc + (size_t)DIM * DIM;
  bf16* Wvc = Wkc + (size_t)DIM * DIM;
  bf16* Q   = Wvc + (size_t)DIM * DIM;
  bf16* Kb  = Q   + (size_t)SEQ * DIM;
  bf16* Vt  = Kb  + (size_t)SEQ * DIM;
  bf16* P   = Vt  + (size_t)DIM * SEQ;
  float* denom  = (float*)(P + (size_t)SEQ * SEQ);
  bf16* partial = (bf16*)(denom + SEQ);

  const int nx = SEQ * DIM;   // 3,145,728
  const int nw = DIM * DIM;   //   589,824
  const int conv_blocks = nx / 2048 + 3 * (nw / 2048);  // 2400

  convert_all_kernel<<<conv_blocks, 256, 0, stream>>>(
      x_raw, Wq_raw, Wk_raw, Wv_raw, xc, Wqc, Wkc, Wvc, denom);
  qkv_kernel<<<dim3(SEQ / 128, 2304 / 128), 256, 0, stream>>>(xc, Wqc, Wkc, Wvc, Q, Kb, Vt);
  score_kernel<<<dim3(SEQ / 128, SEQ / 128), 256, 0, stream>>>(Q, Kb, P, denom);
  pv_kernel<<<dim3(SEQ / 128, DIM / 128, 4), 256, 0, stream>>>(P, Vt, partial);
  reduce_kernel<<<nx / 8 / 256, 256, 0, stream>>>(partial, denom, out);
}

// Round 8
// 166.460 us; speedup vs baseline: 1.0240x; 1.0240x over previous
//
#include <hip/hip_runtime.h>
#include <hip/hip_bf16.h>

using bf16 = __hip_bfloat16;
typedef __attribute__((ext_vector_type(4))) float f32x4;
typedef __attribute__((ext_vector_type(8))) short short8;

#define SEQ 4096
#define DIM 768

// r17: revert r16's counted-vmcnt ring (score 46.5us > r15's <=43.3 ->
// measured regression; 4th flat/negative pipelining attempt = verdict).
// Back to r15 drain core, now parameterized BKC = 32-K chunks per barrier
// iteration. score/qkv: BKC=3 (BK=96) -> 8 iters instead of 12 (-33%
// barrier pairs), LDS 48KB/block = still 3 blocks/CU (avoids m132's
// BK=128 occupancy drop). pv frozen at BKC=2. Layouts (r14 fragment-tiled,
// 0 bank conflicts, contiguous-1KB staging) and epilogues frozen.
// r15: 167.6us, r16: 170.5us; predicted ~158-163us, absmax bit-identical.

__device__ __forceinline__ size_t tiled_off(int r, int c, int K) {
  // bf16-element offset of (r,c) in a fragment-tiled [R][K] matrix
  return (size_t)(r >> 4) * 16 * K + ((size_t)(c >> 5) << 9) +
         (size_t)((((c >> 3) & 3) << 4) + (r & 15)) * 8 + (c & 7);
}

// ---- fused fp32 -> bf16 canonicalization (RNE) + denom zeroing ----
// writes bf16 in fragment-tiled layout (16B chunks -> one slot each)
__global__ void convert_all_kernel(const float* __restrict__ x,
                                   const float* __restrict__ wq,
                                   const float* __restrict__ wk,
                                   const float* __restrict__ wv,
                                   bf16* __restrict__ xc, bf16* __restrict__ wqc,
                                   bf16* __restrict__ wkc, bf16* __restrict__ wvc,
                                   float* __restrict__ denom) {
  const int XB = (SEQ * DIM) / 2048;   // 1536
  const int WB = (DIM * DIM) / 2048;   // 288
  int b = blockIdx.x;
  if (b == 0) {  // zero denom[4096]
    float4 z = {0.f, 0.f, 0.f, 0.f};
#pragma unroll
    for (int q = 0; q < 4; q++)
      *(float4*)(denom + threadIdx.x * 4 + q * 1024) = z;
  }
  const float* src; bf16* dst; int off;
  if (b < XB)               { src = x;  dst = xc;  off = b * 2048; }
  else if (b < XB + WB)     { src = wq; dst = wqc; off = (b - XB) * 2048; }
  else if (b < XB + 2 * WB) { src = wk; dst = wkc; off = (b - XB - WB) * 2048; }
  else                      { src = wv; dst = wvc; off = (b - XB - 2 * WB) * 2048; }
  int i = off + threadIdx.x * 8;       // flat index; 8 | i
  float4 f0 = *(const float4*)(src + i);
  float4 f1 = *(const float4*)(src + i + 4);
  bf16 tmp[8];
  tmp[0] = __float2bfloat16(f0.x); tmp[1] = __float2bfloat16(f0.y);
  tmp[2] = __float2bfloat16(f0.z); tmp[3] = __float2bfloat16(f0.w);
  tmp[4] = __float2bfloat16(f1.x); tmp[5] = __float2bfloat16(f1.y);
  tmp[6] = __float2bfloat16(f1.z); tmp[7] = __float2bfloat16(f1.w);
  int r = i / DIM, c = i % DIM;        // c multiple of 8
  *(uint4*)(dst + tiled_off(r, c, DIM)) = *(const uint4*)tmp;
}

// ============ shared helpers ============
__device__ __forceinline__ void gload_lds16(const bf16* g, bf16* l) {
  __builtin_amdgcn_global_load_lds(
      (const __attribute__((address_space(1))) void*)g,
      (__attribute__((address_space(3))) void*)l,
      16, 0, 0);
}

// ============ BT-GEMM core, tiled operands, drain-style (r15), BKC chunks
// per barrier iteration. LDS per operand: BKC * 8 subtiles * 512 bf16.
template <int BKC>
__device__ __forceinline__ void gemm_core_t(const bf16* __restrict__ At,
                                            const bf16* __restrict__ Bt,
                                            int Kblk /* K/32 */, int nkt,
                                            int m0, int n0, int kt0,
                                            f32x4 acc[4][4],
                                            bf16* lA, bf16* lB) {
  const int tid  = threadIdx.x;
  const int wave = tid >> 6, lane = tid & 63;
  const int sma = (wave & 1) * 4;   // A subtile base (0 or 4)
  const int smb = (wave >> 1) * 4;  // B subtile base
  const int rtA = m0 >> 4, rtB = n0 >> 4;
  for (int t = 0; t < nkt; t += BKC) {
#pragma unroll
    for (int kc = 0; kc < BKC; kc++)
#pragma unroll
      for (int s = 0; s < 2; s++) {
        const int st = wave * 2 + s;   // subtile 0..7 (rows st*16..+16)
        gload_lds16(At + ((size_t)(rtA + st) * Kblk + kt0 + t + kc) * 512 + lane * 8,
                    lA + (kc * 8 + st) * 512);
        gload_lds16(Bt + ((size_t)(rtB + st) * Kblk + kt0 + t + kc) * 512 + lane * 8,
                    lB + (kc * 8 + st) * 512);
      }
    __syncthreads();  // vmcnt drain (DMA done) + barrier
#pragma unroll
    for (int kc = 0; kc < BKC; kc++) {
      short8 af[4], bfr[4];
#pragma unroll
      for (int i = 0; i < 4; i++)
        af[i] = *(const short8*)&lA[(kc * 8 + sma + i) * 512 + lane * 8];
#pragma unroll
      for (int j = 0; j < 4; j++)
        bfr[j] = *(const short8*)&lB[(kc * 8 + smb + j) * 512 + lane * 8];
#pragma unroll
      for (int i = 0; i < 4; i++)
#pragma unroll
        for (int j = 0; j < 4; j++)
          acc[i][j] = __builtin_amdgcn_mfma_f32_16x16x32_bf16(af[i], bfr[j], acc[i][j], 0, 0, 0);
    }
    __syncthreads();
  }
}

// C/D layout (verified m89/m91): col = lane&15, row = (lane>>4)*4 + reg.

// ---- K1: fused QKV projection. grid (32, 18), XCD-swizzled. Q gets softmax
// scale folded; Q/Kb written fragment-tiled; V written transposed+tiled.
__global__ __launch_bounds__(256, 3) void qkv_kernel(
    const bf16* __restrict__ x, const bf16* __restrict__ Wq,
    const bf16* __restrict__ Wk, const bf16* __restrict__ Wv,
    bf16* __restrict__ Q, bf16* __restrict__ Kb, bf16* __restrict__ Vt) {
  __shared__ __align__(16) bf16 smem[24576];  // 48KB: lA(24K) | lB(24K)
  bf16* lA = smem;
  bf16* lB = smem + 12288;
  // swizzle: XCD (id%8) gets m-slab of 4 tiles x all 18 n-tiles (x-slab hot in L2)
  const int id  = blockIdx.y * 32 + blockIdx.x;  // 0..575
  const int xcd = id & 7;
  const int k   = id >> 3;                       // 0..71
  const int m0  = (xcd * 4 + (k & 3)) * 128;
  const int n0g = (k >> 2) * 128;                // 0..17 tiles
  const int wsel = n0g / DIM;          // 0=Q 1=K 2=V (uniform per block)
  const int n0   = n0g % DIM;
  const bf16* W = (wsel == 0) ? Wq : (wsel == 1) ? Wk : Wv;
  f32x4 acc[4][4] = {};
  gemm_core_t<3>(x, W, DIM / 32, DIM / 32, m0, n0, 0, acc, lA, lB);

  const int tid = threadIdx.x, wave = tid >> 6, lane = tid & 63;
  const int wm = (wave & 1) * 64, wn = (wave >> 1) * 64;
  const int g = lane >> 4, lr = lane & 15;
  const float scale = 0.03608439182435161f;  // 1/sqrt(768)

  if (wsel == 2) {
    // Two-phase 128x64 LDS transpose; stride 67 spreads banks.
    bf16* tile = smem;
#pragma unroll
    for (int ph = 0; ph < 2; ph++) {
      __syncthreads();
      if ((wave >> 1) == ph) {
#pragma unroll
        for (int i = 0; i < 4; i++)
#pragma unroll
          for (int j = 0; j < 4; j++)
#pragma unroll
            for (int r = 0; r < 4; r++)
              tile[(wm + i * 16 + g * 4 + r) * 67 + j * 16 + lr] =
                  __float2bfloat16(acc[i][j][r]);
      }
      __syncthreads();
      int cl = tid >> 2;          // column within this 64-col half
      int r0 = (tid & 3) * 32;    // row segment (mult of 32)
      bf16 vals[32];
#pragma unroll
      for (int q = 0; q < 32; q++) vals[q] = tile[(r0 + q) * 67 + cl];
      // Vt fragment-tiled: row n (V output col), k = seq (m0+r0+q), K=SEQ.
      int n = n0 + ph * 64 + cl;
      size_t vbase = (size_t)(n >> 4) * 16 * SEQ +
                     ((size_t)((m0 + r0) >> 5) << 9) + (size_t)(n & 15) * 8;
#pragma unroll
      for (int qb = 0; qb < 4; qb++)   // chunk qb -> +qb*16 slots = +qb*128 elems
        *(uint4*)(Vt + vbase + qb * 128) = *(const uint4*)(vals + qb * 8);
    }
  } else {
    bf16* dstm = (wsel == 0) ? Q : Kb;
    float fs = (wsel == 0) ? scale : 1.0f;
#pragma unroll
    for (int i = 0; i < 4; i++)
#pragma unroll
      for (int j = 0; j < 4; j++)
#pragma unroll
        for (int r = 0; r < 4; r++) {
          int row = m0 + wm + i * 16 + g * 4 + r;
          int col = n0 + wn + j * 16 + lr;
          dstm[tiled_off(row, col, DIM)] = __float2bfloat16(acc[i][j][r] * fs);
        }
  }
}

// ---- K2: S = Q K^T; P = exp(S); row sums -> denom. grid (32,32),
// XCD-swizzled, BK=96 drain core on tiled Q/Kb; P written tiled.
__global__ __launch_bounds__(256, 3) void score_kernel(
    const bf16* __restrict__ Q, const bf16* __restrict__ Kb,
    bf16* __restrict__ P, float* __restrict__ denom) {
  __shared__ __align__(16) bf16 smem[24576];   // 48KB
  bf16* lA = smem;
  bf16* lB = smem + 12288;
  // swizzle: XCD (id%8) gets m-slab of 4 Q-tiles (L2-hot) x all 32 n.
  const int id  = blockIdx.y * 32 + blockIdx.x;  // 0..1023
  const int xcd = id & 7;
  const int k   = id >> 3;                       // 0..127
  const int m0  = (xcd * 4 + (k & 3)) * 128;
  const int n0  = (k >> 2) * 128;
  f32x4 acc[4][4] = {};
  gemm_core_t<3>(Q, Kb, DIM / 32, DIM / 32, m0, n0, 0, acc, lA, lB);

  const int tid = threadIdx.x, wave = tid >> 6, lane = tid & 63;
  const int wm = (wave & 1) * 64, wn = (wave >> 1) * 64;
  const int g = lane >> 4, lr = lane & 15;
#pragma unroll
  for (int i = 0; i < 4; i++) {
    float rsum[4] = {0.f, 0.f, 0.f, 0.f};
#pragma unroll
    for (int j = 0; j < 4; j++)
#pragma unroll
      for (int r = 0; r < 4; r++) {
        float p = __expf(acc[i][j][r]);
        int row = m0 + wm + i * 16 + g * 4 + r;
        int col = n0 + wn + j * 16 + lr;
        P[tiled_off(row, col, SEQ)] = __float2bfloat16(p);
        rsum[r] += p;
      }
#pragma unroll
    for (int r = 0; r < 4; r++) {
      float s = rsum[r];
      s += __shfl_xor(s, 1);
      s += __shfl_xor(s, 2);
      s += __shfl_xor(s, 4);
      s += __shfl_xor(s, 8);
      if (lr == 0) atomicAdd(&denom[m0 + wm + i * 16 + g * 4 + r], s);
    }
  }
}

// ---- K3a: split-K PV. grid (32, 6, 4), XCD-swizzled. bf16 partials
// (row-major, consumed linearly by reduce). BKC=2 (frozen r15 config).
__global__ __launch_bounds__(256, 3) void pv_kernel(
    const bf16* __restrict__ P, const bf16* __restrict__ Vt,
    bf16* __restrict__ partial) {
  __shared__ __align__(16) bf16 smem[16384];   // 32KB
  bf16* lA = smem;
  bf16* lB = smem + 8192;
  // swizzle: XCD gets 3 (z,n) pairs x all 32 m: Vt chunk L2-hot
  // across the 32 consecutive same-XCD blocks that reuse it.
  const int id  = (blockIdx.z * 6 + blockIdx.y) * 32 + blockIdx.x;  // 0..767
  const int xcd = id & 7;
  const int k   = id >> 3;          // 0..95
  const int m0  = (k & 31) * 128;
  const int pairid = xcd * 3 + (k >> 5);  // 0..23
  const int zz  = pairid / 6;
  const int n0  = (pairid % 6) * 128;
  f32x4 acc[4][4] = {};
  // K-window: kts [zz*32, zz*32+32) of SEQ/32=128
  gemm_core_t<2>(P, Vt, SEQ / 32, 32, m0, n0, zz * 32, acc, lA, lB);

  bf16* pout = partial + (size_t)zz * SEQ * DIM;
  const int tid = threadIdx.x, wave = tid >> 6, lane = tid & 63;
  const int wm = (wave & 1) * 64, wn = (wave >> 1) * 64;
  const int g = lane >> 4, lr = lane & 15;
#pragma unroll
  for (int i = 0; i < 4; i++)
#pragma unroll
    for (int j = 0; j < 4; j++)
#pragma unroll
      for (int r = 0; r < 4; r++) {
        int row = m0 + wm + i * 16 + g * 4 + r;
        int col = n0 + wn + j * 16 + lr;
        pout[row * DIM + col] = __float2bfloat16(acc[i][j][r]);
      }
}

// ---- K3b: out = (sum_z partial[z]) / denom[row]. 8 elems/thread.
__global__ __launch_bounds__(256) void reduce_kernel(
    const bf16* __restrict__ partial, const float* __restrict__ denom,
    float* __restrict__ out) {
  const size_t stride = (size_t)SEQ * DIM;
  int i = (blockIdx.x * 256 + threadIdx.x) * 8;
  uint4 u0 = *(const uint4*)(partial + i);
  uint4 u1 = *(const uint4*)(partial + stride + i);
  uint4 u2 = *(const uint4*)(partial + 2 * stride + i);
  uint4 u3 = *(const uint4*)(partial + 3 * stride + i);
  bf16 a0[8], a1[8], a2[8], a3[8];
  *(uint4*)a0 = u0; *(uint4*)a1 = u1; *(uint4*)a2 = u2; *(uint4*)a3 = u3;
  float inv = 1.0f / denom[i / DIM];   // 8 | DIM: all 8 elems same row
  float o[8];
#pragma unroll
  for (int k = 0; k < 8; k++)
    o[k] = (__bfloat162float(a0[k]) + __bfloat162float(a1[k]) +
            __bfloat162float(a2[k]) + __bfloat162float(a3[k])) * inv;
  *(float4*)(out + i)     = *(const float4*)(o);
  *(float4*)(out + i + 4) = *(const float4*)(o + 4);
}

extern "C" void kernel_launch(void* const* d_in, const int* in_sizes, int n_in,
                              void* d_out, int out_size, void* d_ws, size_t ws_size,
                              hipStream_t stream) {
  const float* x_raw  = (const float*)d_in[0];
  const float* Wq_raw = (const float*)d_in[1];
  const float* Wk_raw = (const float*)d_in[2];
  const float* Wv_raw = (const float*)d_in[3];
  float* out = (float*)d_out;

  // ws layout (~86 MB): all GEMM operands fragment-tiled (same sizes)
  bf16* xc  = (bf16*)d_ws;
  bf16* Wqc = xc  + (size_t)SEQ * DIM;
  bf16* Wkc = Wqc + (size_t)DIM * DIM;
  bf16* Wvc = Wkc + (size_t)DIM * DIM;
  bf16* Q   = Wvc + (size_t)DIM * DIM;
  bf16* Kb  = Q   + (size_t)SEQ * DIM;
  bf16* Vt  = Kb  + (size_t)SEQ * DIM;
  bf16* P   = Vt  + (size_t)DIM * SEQ;
  float* denom  = (float*)(P + (size_t)SEQ * SEQ);
  bf16* partial = (bf16*)(denom + SEQ);

  const int nx = SEQ * DIM;   // 3,145,728
  const int nw = DIM * DIM;   //   589,824
  const int conv_blocks = nx / 2048 + 3 * (nw / 2048);  // 2400

  convert_all_kernel<<<conv_blocks, 256, 0, stream>>>(
      x_raw, Wq_raw, Wk_raw, Wv_raw, xc, Wqc, Wkc, Wvc, denom);
  qkv_kernel<<<dim3(SEQ / 128, 2304 / 128), 256, 0, stream>>>(xc, Wqc, Wkc, Wvc, Q, Kb, Vt);
  score_kernel<<<dim3(SEQ / 128, SEQ / 128), 256, 0, stream>>>(Q, Kb, P, denom);
  pv_kernel<<<dim3(SEQ / 128, DIM / 128, 4), 256, 0, stream>>>(P, Vt, partial);
  reduce_kernel<<<nx / 8 / 256, 256, 0, stream>>>(partial, denom, out);
}